// Round 10
// baseline (150.706 us; speedup 1.0000x reference)
//
#include <hip/hip_runtime.h>

namespace {

constexpr int Hh   = 256;
constexpr int Ww   = 256;
constexpr int IMG  = Hh * Ww;            // 65536
constexpr int NV   = (Hh - 1) * Ww;      // 65280 vertical candidates
constexpr int NC   = NV + Hh * (Ww - 1); // 130560 total candidates
constexpr int PMAX = 8192;
constexpr int CB   = 256;                // candidate block
constexpr int NCB  = (NC + CB - 1) / CB; // 510
constexpr int NB   = 4;                  // batch
constexpr int NIMG = 2 * NB;             // 8 images (pred 0..3, gt 4..7)
constexpr float EPSF = 1e-8f;
constexpr int TCH  = 8;                  // chamfer target chunks
constexpr int CHK  = PMAX / TCH;         // 1024 targets per chunk (8 KB LDS)
constexpr int QB   = PMAX / CB;          // 32 query blocks per combo
constexpr int NGRP = NIMG * TCH;         // 64 level-1 ticket groups
constexpr int TPAD = 32;                 // ints between tickets (128 B lines)

// Candidate c -> (point, valid). Vertical block (row-major over (H-1)xW)
// then horizontal block (row-major over Hx(W-1)), matching the reference.
// Compaction is ORDER-PRESERVING (prefix-sum ranks) -> exact reference
// first-8192 truncation semantics.
__device__ inline bool cand_pt(const float* img, int c, float2& pt) {
  if (c < NV) {
    int i = c >> 8, j = c & 255;             // W == 256
    float v1 = img[i * Ww + j];
    float v2 = img[(i + 1) * Ww + j];
    bool valid = (v1 == 0.f) | (v2 == 0.f) | (v1 * v2 < 0.f);
    float a = fabsf(v1) / (fabsf(v1) + fabsf(v2) + EPSF);
    float row = (v1 == 0.f) ? (float)i
              : ((v2 == 0.f) ? (float)(i + 1) : (float)i + a);
    pt.x = row; pt.y = (float)j;
    return valid;
  } else {
    int cc = c - NV;
    int i = cc / (Ww - 1);
    int j = cc - i * (Ww - 1);
    float h1 = img[i * Ww + j];
    float h2 = img[i * Ww + j + 1];
    bool valid = (h1 == 0.f) | (h2 == 0.f) | (h1 * h2 < 0.f);
    float a = fabsf(h1) / (fabsf(h1) + fabsf(h2) + EPSF);
    float col = (h1 == 0.f) ? (float)j
              : ((h2 == 0.f) ? (float)(j + 1) : (float)j + a);
    pt.x = (float)i; pt.y = col;
    return valid;
  }
}

__device__ inline const float* img_ptr(const float* pred, const float* gt, int img) {
  return (img < NB) ? pred + img * IMG : gt + (img - NB) * IMG;
}

// Kernel 1: per-block valid counts (plain store), minq re-init, L1 partials,
// and ticket re-zero (one block). No atomics anywhere.
__global__ void count_kernel(const float* __restrict__ pred,
                             const float* __restrict__ gt,
                             int* __restrict__ bCounts,
                             float* __restrict__ l1part,
                             unsigned int* __restrict__ minq,
                             int* __restrict__ tick1,
                             int* __restrict__ tick2) {
  int img = blockIdx.y;
  int cb  = blockIdx.x;
  const float* im = img_ptr(pred, gt, img);
  int tid = threadIdx.x;
  int c = cb * CB + tid;
  int lane = tid & 63, wid = tid >> 6;

  // fused: re-zero tickets for kernel 3 (kernel boundary -> visible)
  if (img == 0 && cb == 0) {
    if (tid < NGRP) tick1[tid * TPAD] = 0;
    if (tid == NGRP) *tick2 = 0;
  }

  // fused: re-init minq (combo index space == img index space, 8*8192)
  if (cb < PMAX / CB)
    minq[img * PMAX + c] = 0x7F7F7F7Fu;          // ~3.39e38 as float

  bool valid = false;
  float2 pt;
  if (c < NC) valid = cand_pt(im, c, pt);
  unsigned long long bal = __ballot(valid);

  __shared__ int   iw[CB / 64];
  __shared__ float wred[CB / 64];
  if (lane == 0) iw[wid] = __popcll(bal);
  __syncthreads();
  if (tid == 0)
    bCounts[img * NCB + cb] = iw[0] + iw[1] + iw[2] + iw[3];

  // fused L1 partial (pred images only; pixel blocks only; c < IMG there)
  if (img < NB && cb < IMG / CB) {
    float v = fabsf(pred[img * IMG + c] - gt[img * IMG + c]);
    for (int off = 32; off > 0; off >>= 1) v += __shfl_down(v, off, 64);
    if (lane == 0) wred[wid] = v;
    __syncthreads();
    if (tid == 0)
      l1part[img * (IMG / CB) + cb] = wred[0] + wred[1] + wred[2] + wred[3];
  }
}

// Kernel 2: order-preserving compacted write. Each block recomputes its own
// exclusive prefix over bCounts[img][0..cb) (<=510 ints, L2-hot). Last block
// per image also writes counts[img].
__global__ void write_kernel(const float* __restrict__ pred,
                             const float* __restrict__ gt,
                             const int* __restrict__ bCounts,
                             int* __restrict__ counts,
                             float2* __restrict__ pts) {
  int img = blockIdx.y;
  int cb  = blockIdx.x;
  const float* im = img_ptr(pred, gt, img);
  int tid = threadIdx.x;
  int c = cb * CB + tid;
  int lane = tid & 63, wid = tid >> 6;

  bool valid = false;
  float2 pt;
  if (c < NC) valid = cand_pt(im, c, pt);
  unsigned long long bal = __ballot(valid);

  // block-wide prefix of bCounts[img][0..cb)
  int pre = 0;
  for (int t = tid; t < cb; t += CB) pre += bCounts[img * NCB + t];
  for (int off = 32; off > 0; off >>= 1) pre += __shfl_down(pre, off, 64);
  __shared__ int pw[CB / 64];
  __shared__ int iw[CB / 64];
  if (lane == 0) pw[wid] = pre;
  if (lane == 0) iw[wid] = __popcll(bal);
  __syncthreads();
  int sbase = pw[0] + pw[1] + pw[2] + pw[3];       // exclusive image prefix
  int wofs = 0;
  for (int w = 0; w < CB / 64; ++w) wofs += (w < wid) ? iw[w] : 0;

  if (valid) {
    int rank = sbase + wofs + __popcll(bal & ((1ull << lane) - 1ull));
    if (rank < PMAX) pts[img * PMAX + rank] = pt;
  }
  if (cb == NCB - 1 && tid == 0) {
    int total = sbase + iw[0] + iw[1] + iw[2] + iw[3];
    counts[img] = min(total, PMAX);
  }
}

__device__ inline void min_step(float2 p, float2 t, float& m) {
  float dx = p.x - t.x;
  float dy = p.y - t.y;
  m = fminf(m, dx * dx + dy * dy);
}

// Kernel 3: chamfer partial mins + fused final reduction.
// Every block (incl. inactive) passes through a 2-level finish ticket;
// the globally-last block performs the tail reductions + combine.
// minq reads in the tail use agent-scope atomic loads (cross-XCD safe for
// values written by atomicMin within this kernel).
__global__ void chamfer_tail_kernel(const float2* __restrict__ pts,
                                    const int* __restrict__ counts,
                                    const float* __restrict__ l1part,
                                    unsigned int* __restrict__ minq,
                                    int* __restrict__ tick1,
                                    int* __restrict__ tick2,
                                    float* __restrict__ out) {
  __shared__ float2 tgt[CHK];
  __shared__ int lastFlag;
  __shared__ float csum[NIMG];
  __shared__ float sdf[NB];
  int tid = threadIdx.x;

  int b   = blockIdx.z & (NB - 1);
  int dir = blockIdx.z / NB;
  int qimg = (dir == 0) ? b : NB + b;
  int timg = (dir == 0) ? NB + b : b;
  int nq = counts[qimg], nt = counts[timg];
  int qbase = blockIdx.x * CB;

  bool active = (nq > 0) && (nt > 0) && (qbase < nq);   // block-uniform
  int ts = 0, cnt = 0;
  if (active) {
    int len = (nt + TCH - 1) / TCH;
    ts = blockIdx.y * len;
    if (ts >= nt) active = false;
    else cnt = min(len, nt - ts);
  }

  if (active) {
    for (int t = tid; t < cnt; t += CB)
      tgt[t] = pts[timg * PMAX + ts + t];
    __syncthreads();

    int q = qbase + tid;
    float2 p = (q < nq) ? pts[qimg * PMAX + q] : make_float2(0.f, 0.f);
    float m0 = 3.4e38f, m1 = 3.4e38f, m2 = 3.4e38f, m3 = 3.4e38f;
    int j = 0;
    for (; j + 4 <= cnt; j += 4) {                 // 4 independent min chains
      min_step(p, tgt[j + 0], m0);
      min_step(p, tgt[j + 1], m1);
      min_step(p, tgt[j + 2], m2);
      min_step(p, tgt[j + 3], m3);
    }
    for (; j < cnt; ++j) min_step(p, tgt[j], m0);
    float m = fminf(fminf(m0, m1), fminf(m2, m3));
    if (q < nq)
      atomicMin(&minq[(dir * NB + b) * PMAX + q], __float_as_uint(m));
  }

  // ---- finish tickets (all blocks) ----
  __threadfence();                                 // release minq writes
  if (tid == 0) {
    int last = 0;
    int g = blockIdx.z * TCH + blockIdx.y;         // 64 groups of QB blocks
    int o1 = atomicAdd(&tick1[g * TPAD], 1);
    if (o1 == QB - 1) {                            // last block of group
      int o2 = atomicAdd(tick2, 1);
      last = (o2 == NGRP - 1);                     // globally last
    }
    lastFlag = last;
  }
  __syncthreads();
  if (!lastFlag) return;
  __threadfence();                                 // acquire all minq writes

  // ---- fused tail (runs in exactly one block) ----
  {                                                // chamfer sqrt-sums
    int combo = tid >> 5;                          // 0..7
    int sl    = tid & 31;
    int dirc = combo / NB, bc = combo & (NB - 1);
    int qi = (dirc == 0) ? bc : NB + bc;
    int n = counts[qi];
    float s = 0.f;
    for (int q = sl; q < n; q += 32) {
      unsigned int u = __hip_atomic_load(&minq[combo * PMAX + q],
                                         __ATOMIC_RELAXED,
                                         __HIP_MEMORY_SCOPE_AGENT);
      s += sqrtf(__uint_as_float(u));
    }
    for (int off = 16; off > 0; off >>= 1) s += __shfl_down(s, off, 32);
    if (sl == 0) csum[combo] = s;
  }
  {                                                // L1 sums (K1 output; plain)
    int w = tid >> 6;                              // 0..3 = sample
    int l = tid & 63;
    const float* lp = l1part + w * (IMG / CB);
    float s = lp[l] + lp[l + 64] + lp[l + 128] + lp[l + 192];
    for (int off = 32; off > 0; off >>= 1) s += __shfl_down(s, off, 64);
    if (l == 0) sdf[w] = s;
  }
  __syncthreads();
  if (tid == 0) {
    float total = 0.f;
    for (int bb = 0; bb < NB; ++bb) {
      float n1 = (float)counts[bb];
      float n2 = (float)counts[NB + bb];
      float mean1 = csum[bb]      / fmaxf(n1, 1.f);
      float mean2 = csum[NB + bb] / fmaxf(n2, 1.f);
      float cd = -mean1 + mean2;
      float ch = (n1 > 0.f && n2 > 0.f) ? fabsf(cd) : 0.f;
      total += ch + sdf[bb] * (1.f / (float)IMG);
    }
    out[0] = total * (1.f / (float)NB);
  }
}

} // namespace

extern "C" void kernel_launch(void* const* d_in, const int* in_sizes, int n_in,
                              void* d_out, int out_size, void* d_ws, size_t ws_size,
                              hipStream_t stream) {
  const float* pred = (const float*)d_in[0];
  const float* gt   = (const float*)d_in[1];
  float* out = (float*)d_out;

  char* ws = (char*)d_ws;
  // layout (bytes):
  //   [0, +32)          int counts[8]        (written by write_kernel)
  //   [1024, +8192)     int tick1[64*32]     (padded; zeroed in count_kernel)
  //   [9216, +4)        int tick2            (zeroed in count_kernel)
  //   [16384, +16320)   int bCounts[8*510]
  //   [36864, +4096)    float l1part[4*256]
  //   [65536, +524288)  float2 pts[8*8192]
  //   [1048576,+262144) uint minq[8*8192]    (re-init in count_kernel)
  int*          counts  = (int*)(ws + 0);
  int*          tick1   = (int*)(ws + 1024);
  int*          tick2   = (int*)(ws + 9216);
  int*          bCounts = (int*)(ws + 16384);
  float*        l1part  = (float*)(ws + 36864);
  float2*       pts     = (float2*)(ws + 65536);
  unsigned int* minq    = (unsigned int*)(ws + 1048576);

  count_kernel<<<dim3(NCB, NIMG), CB, 0, stream>>>(pred, gt, bCounts, l1part,
                                                   minq, tick1, tick2);
  write_kernel<<<dim3(NCB, NIMG), CB, 0, stream>>>(pred, gt, bCounts, counts, pts);
  chamfer_tail_kernel<<<dim3(QB, TCH, NIMG), CB, 0, stream>>>(pts, counts, l1part,
                                                              minq, tick1, tick2,
                                                              out);
}

// Round 11
// 40.438 us; speedup vs baseline: 3.7268x; 3.7268x over previous
//
#include <hip/hip_runtime.h>

namespace {

constexpr int Hh   = 256;
constexpr int Ww   = 256;
constexpr int IMG  = Hh * Ww;            // 65536
constexpr int NV   = (Hh - 1) * Ww;      // 65280 vertical candidates
constexpr int NC   = NV + Hh * (Ww - 1); // 130560 total candidates
constexpr int PMAX = 8192;
constexpr int CB   = 256;                // candidate block
constexpr int NCB  = (NC + CB - 1) / CB; // 510
constexpr int NB   = 4;                  // batch
constexpr int NIMG = 2 * NB;             // 8 images (pred 0..3, gt 4..7)
constexpr float EPSF = 1e-8f;
constexpr int TCH  = 8;                  // chamfer target chunks
constexpr int CHK  = PMAX / TCH;         // 1024 targets per chunk (8 KB LDS)

// Candidate c -> (point, valid). Vertical block (row-major over (H-1)xW)
// then horizontal block (row-major over Hx(W-1)), matching the reference.
// Compaction is ORDER-PRESERVING (prefix-sum ranks) -> exact reference
// first-8192 truncation semantics.
__device__ inline bool cand_pt(const float* img, int c, float2& pt) {
  if (c < NV) {
    int i = c >> 8, j = c & 255;             // W == 256
    float v1 = img[i * Ww + j];
    float v2 = img[(i + 1) * Ww + j];
    bool valid = (v1 == 0.f) | (v2 == 0.f) | (v1 * v2 < 0.f);
    float a = fabsf(v1) / (fabsf(v1) + fabsf(v2) + EPSF);
    float row = (v1 == 0.f) ? (float)i
              : ((v2 == 0.f) ? (float)(i + 1) : (float)i + a);
    pt.x = row; pt.y = (float)j;
    return valid;
  } else {
    int cc = c - NV;
    int i = cc / (Ww - 1);
    int j = cc - i * (Ww - 1);
    float h1 = img[i * Ww + j];
    float h2 = img[i * Ww + j + 1];
    bool valid = (h1 == 0.f) | (h2 == 0.f) | (h1 * h2 < 0.f);
    float a = fabsf(h1) / (fabsf(h1) + fabsf(h2) + EPSF);
    float col = (h1 == 0.f) ? (float)j
              : ((h2 == 0.f) ? (float)(j + 1) : (float)j + a);
    pt.x = (float)i; pt.y = col;
    return valid;
  }
}

__device__ inline const float* img_ptr(const float* pred, const float* gt, int img) {
  return (img < NB) ? pred + img * IMG : gt + (img - NB) * IMG;
}

// Kernel 1: per-block valid counts (plain store), minq re-init, L1 partials.
// No atomics anywhere. (Verbatim round-3 body.)
__global__ void count_kernel(const float* __restrict__ pred,
                             const float* __restrict__ gt,
                             int* __restrict__ bCounts,
                             float* __restrict__ l1part,
                             unsigned int* __restrict__ minq) {
  int img = blockIdx.y;
  int cb  = blockIdx.x;
  const float* im = img_ptr(pred, gt, img);
  int tid = threadIdx.x;
  int c = cb * CB + tid;
  int lane = tid & 63, wid = tid >> 6;

  // fused: re-init minq (combo index space == img index space, 8*8192)
  if (cb < PMAX / CB)
    minq[img * PMAX + c] = 0x7F7F7F7Fu;          // ~3.39e38 as float

  bool valid = false;
  float2 pt;
  if (c < NC) valid = cand_pt(im, c, pt);
  unsigned long long bal = __ballot(valid);

  __shared__ int   iw[CB / 64];
  __shared__ float wred[CB / 64];
  if (lane == 0) iw[wid] = __popcll(bal);
  __syncthreads();
  if (tid == 0)
    bCounts[img * NCB + cb] = iw[0] + iw[1] + iw[2] + iw[3];

  // fused L1 partial (pred images only; pixel blocks only; c < IMG there)
  if (img < NB && cb < IMG / CB) {
    float v = fabsf(pred[img * IMG + c] - gt[img * IMG + c]);
    for (int off = 32; off > 0; off >>= 1) v += __shfl_down(v, off, 64);
    if (lane == 0) wred[wid] = v;
    __syncthreads();
    if (tid == 0)
      l1part[img * (IMG / CB) + cb] = wred[0] + wred[1] + wred[2] + wred[3];
  }
}

// Kernel 2: per-image exclusive scan of the 510 block counts (one block/image).
// (Verbatim round-3 body.)
__global__ void scan_kernel(const int* __restrict__ bCounts,
                            int* __restrict__ bOffs,
                            int* __restrict__ counts) {
  int img = blockIdx.x;
  __shared__ int s[512];
  int t = threadIdx.x;
  int v = (t < NCB) ? bCounts[img * NCB + t] : 0;
  s[t] = v;
  __syncthreads();
  for (int off = 1; off < 512; off <<= 1) {
    int x = s[t];
    int y = (t >= off) ? s[t - off] : 0;
    __syncthreads();
    s[t] = x + y;
    __syncthreads();
  }
  if (t < NCB) bOffs[img * NCB + t] = s[t] - v;   // exclusive prefix
  if (t == 511) counts[img] = min(s[511], PMAX);  // n = min(valid, 8192)
}

// Kernel 3: order-preserving compaction into pts[img][rank], rank < PMAX.
// (Verbatim round-3 body.)
__global__ void write_kernel(const float* __restrict__ pred,
                             const float* __restrict__ gt,
                             const int* __restrict__ bOffs,
                             float2* __restrict__ pts) {
  int img = blockIdx.y;
  const float* im = img_ptr(pred, gt, img);
  int c = blockIdx.x * CB + threadIdx.x;
  bool valid = false;
  float2 pt;
  if (c < NC) valid = cand_pt(im, c, pt);
  unsigned long long b = __ballot(valid);
  __shared__ int wofs[CB / 64];
  int lane = threadIdx.x & 63, wid = threadIdx.x >> 6;
  if (lane == 0) wofs[wid] = __popcll(b);
  __syncthreads();
  if (threadIdx.x == 0) {
    int run = 0;
    for (int w = 0; w < CB / 64; ++w) { int t = wofs[w]; wofs[w] = run; run += t; }
  }
  __syncthreads();
  if (valid) {
    int rank = bOffs[img * NCB + blockIdx.x] + wofs[wid]
             + __popcll(b & ((1ull << lane) - 1ull));
    if (rank < PMAX) pts[img * PMAX + rank] = pt;
  }
}

__device__ inline void min_step(float2 p, float2 t, float& m) {
  float dx = p.x - t.x;
  float dy = p.y - t.y;
  m = fminf(m, dx * dx + dy * dy);
}

// Kernel 4: partial chamfer. grid = (PMAX/256 qblocks, TCH tchunks, 2*NB).
// atomicMin to 64K distinct addresses (no contention). (Verbatim round-3 body.)
__global__ void chamfer_kernel(const float2* __restrict__ pts,
                               const int* __restrict__ counts,
                               unsigned int* __restrict__ minq) {
  int b   = blockIdx.z & (NB - 1);
  int dir = blockIdx.z / NB;
  int qimg = (dir == 0) ? b : NB + b;
  int timg = (dir == 0) ? NB + b : b;
  int nq = counts[qimg], nt = counts[timg];
  if (nq == 0 || nt == 0) return;                  // block-uniform
  int qbase = blockIdx.x * 256;
  if (qbase >= nq) return;
  int len = (nt + TCH - 1) / TCH;
  int ts  = blockIdx.y * len;
  if (ts >= nt) return;
  int cnt = min(len, nt - ts);

  __shared__ float2 tgt[CHK];
  for (int t = threadIdx.x; t < cnt; t += 256)
    tgt[t] = pts[timg * PMAX + ts + t];
  __syncthreads();

  int q = qbase + threadIdx.x;
  float2 p = (q < nq) ? pts[qimg * PMAX + q] : make_float2(0.f, 0.f);
  float m0 = 3.4e38f, m1 = 3.4e38f, m2 = 3.4e38f, m3 = 3.4e38f;
  int j = 0;
  for (; j + 4 <= cnt; j += 4) {                   // 4 independent min chains
    min_step(p, tgt[j + 0], m0);
    min_step(p, tgt[j + 1], m1);
    min_step(p, tgt[j + 2], m2);
    min_step(p, tgt[j + 3], m3);
  }
  for (; j < cnt; ++j) min_step(p, tgt[j], m0);
  float m = fminf(fminf(m0, m1), fminf(m2, m3));

  if (q < nq)
    atomicMin(&minq[(dir * NB + b) * PMAX + q], __float_as_uint(m));
}

// Kernel 5: single-block tail; ALL reductions concurrent in one pass
// (32 lanes per combo for chamfer sums, one wave per sample for L1),
// one barrier, scalar combine. (Round-9 tail body.)
__global__ void tail_kernel(const unsigned int* __restrict__ minq,
                            const int* __restrict__ counts,
                            const float* __restrict__ l1part,
                            float* __restrict__ out) {
  __shared__ float csum[NIMG];
  __shared__ float sdf[NB];
  int tid = threadIdx.x;

  {                                               // chamfer sqrt-sums
    int combo = tid >> 5;                         // 0..7
    int sl    = tid & 31;
    int dir = combo / NB, b = combo & (NB - 1);
    int qimg = (dir == 0) ? b : NB + b;
    int nq = counts[qimg];
    float s = 0.f;
    for (int q = sl; q < nq; q += 32)             // ~64 pipelined loads
      s += sqrtf(__uint_as_float(minq[combo * PMAX + q]));
    for (int off = 16; off > 0; off >>= 1) s += __shfl_down(s, off, 32);
    if (sl == 0) csum[combo] = s;
  }
  {                                               // L1 sums (256 partials/sample)
    int w = tid >> 6;                             // 0..3 = sample
    int l = tid & 63;
    const float* lp = l1part + w * (IMG / CB);
    float s = lp[l] + lp[l + 64] + lp[l + 128] + lp[l + 192];
    for (int off = 32; off > 0; off >>= 1) s += __shfl_down(s, off, 64);
    if (l == 0) sdf[w] = s;
  }
  __syncthreads();
  if (tid == 0) {
    float total = 0.f;
    for (int b = 0; b < NB; ++b) {
      float n1 = (float)counts[b];
      float n2 = (float)counts[NB + b];
      float mean1 = csum[b]      / fmaxf(n1, 1.f);
      float mean2 = csum[NB + b] / fmaxf(n2, 1.f);
      float cd = -mean1 + mean2;
      float ch = (n1 > 0.f && n2 > 0.f) ? fabsf(cd) : 0.f;
      total += ch + sdf[b] * (1.f / (float)IMG);
    }
    out[0] = total * (1.f / (float)NB);
  }
}

} // namespace

extern "C" void kernel_launch(void* const* d_in, const int* in_sizes, int n_in,
                              void* d_out, int out_size, void* d_ws, size_t ws_size,
                              hipStream_t stream) {
  const float* pred = (const float*)d_in[0];
  const float* gt   = (const float*)d_in[1];
  float* out = (float*)d_out;

  char* ws = (char*)d_ws;
  // layout (bytes):
  //   [0, +32)          int counts[8]        (written by scan_kernel)
  //   [4096, +16320)    int bCounts[8*510]
  //   [20480, +16320)   int bOffs[8*510]
  //   [36864, +4096)    float l1part[4*256]
  //   [65536, +524288)  float2 pts[8*8192]
  //   [1048576,+262144) uint minq[8*8192]    (re-init in count_kernel)
  int*          counts  = (int*)(ws + 0);
  int*          bCounts = (int*)(ws + 4096);
  int*          bOffs   = (int*)(ws + 20480);
  float*        l1part  = (float*)(ws + 36864);
  float2*       pts     = (float2*)(ws + 65536);
  unsigned int* minq    = (unsigned int*)(ws + 1048576);

  count_kernel<<<dim3(NCB, NIMG), CB, 0, stream>>>(pred, gt, bCounts, l1part, minq);
  scan_kernel<<<NIMG, 512, 0, stream>>>(bCounts, bOffs, counts);
  write_kernel<<<dim3(NCB, NIMG), CB, 0, stream>>>(pred, gt, bOffs, pts);
  chamfer_kernel<<<dim3(PMAX / CB, TCH, NIMG), 256, 0, stream>>>(pts, counts, minq);
  tail_kernel<<<1, 256, 0, stream>>>(minq, counts, l1part, out);
}